// Round 7
// baseline (417.309 us; speedup 1.0000x reference)
//
#include <hip/hip_runtime.h>
#include <hip/hip_cooperative_groups.h>
#include <cmath>

namespace cg = cooperative_groups;

#define Bz 4
#define Tz 1000
#define Wz 32
#define Dz 200
#define EDz 400
#define Nz 16
#define DTRz 13
#define Lz 1001
#define POSz 500
#define LPz 501
#define TSTR 512
#define ESP 10
#define NEG_BIG -1e30f

__device__ __forceinline__ float wave_sum(float v) {
#pragma unroll
  for (int o = 32; o; o >>= 1) v += __shfl_xor(v, o);
  return v;
}

union SMem {
  struct { float attn[Wz]; float red[4]; float xs[Dz]; } f;
  struct { float Xs[16][68]; float Ws[16][68]; } g;        // 8704 B
  struct { float sred[64][46]; } m;                        // 11776 B
  struct { float dfin[DTRz][64]; } d;                      // 3328 B
};

__global__ __launch_bounds__(256) void k_all(
    const float* __restrict__ x, const int* __restrict__ n_tweets,
    const int* __restrict__ n_words, const float* __restrict__ w_attn,
    const float* __restrict__ b_attn, const float* __restrict__ norm_w,
    const float* __restrict__ cls, const float* __restrict__ out_proj,
    const float* __restrict__ head_w, const float* __restrict__ head_b,
    const float* __restrict__ ipf, const float* __restrict__ ipb,
    const float* __restrict__ cwf, const float* __restrict__ cwb,
    const float* __restrict__ cbf, const float* __restrict__ cbb,
    const float* __restrict__ xpjf, const float* __restrict__ xpjb,
    const float* __restrict__ dtwf, const float* __restrict__ dtwb,
    const float* __restrict__ dtbf, const float* __restrict__ dtbb,
    const float* __restrict__ Alogf, const float* __restrict__ Alogb,
    const float* __restrict__ Dpf, const float* __restrict__ Dpb,
    float* __restrict__ xn, float* __restrict__ Pbuf,
    float* __restrict__ xp_t, float* __restrict__ dt_t,
    float* __restrict__ Bm_t, float* __restrict__ dbcp,
    float* __restrict__ Cend, float* __restrict__ zbuf,
    float* __restrict__ vbuf, float* __restrict__ ybuf,
    float* __restrict__ outp) {
  cg::grid_group grid = cg::this_grid();
  __shared__ SMem sh;
  const int bid = blockIdx.x;
  const int G = gridDim.x;
  const int tid = threadIdx.x;
  const int wave = tid >> 6, lane = tid & 63;

  // ---------------- Phase 0: setup (v, cls->xn/z) + word-pool ----------------
  for (int task = bid; task < 9 + Bz * Tz; task += G) {
    if (task == 0) {
      for (int e = tid; e < EDz; e += 256) {
        float acc = 0.f;
        for (int d = 0; d < Dz; d += 4) {
          float4 ov = *(const float4*)(out_proj + e * Dz + d);
          acc += ov.x * head_w[d] + ov.y * head_w[d + 1] +
                 ov.z * head_w[d + 2] + ov.w * head_w[d + 3];
        }
        vbuf[e] = acc;
      }
    } else if (task < 9) {
      int id = task - 1;
      int br = id >> 2, b = id & 3;
      float val = (tid < Dz) ? cls[tid] : 0.f;
      float sq = wave_sum(val * val);
      if (lane == 0) sh.f.red[wave] = sq;
      __syncthreads();
      float tot = sh.f.red[0] + sh.f.red[1] + sh.f.red[2] + sh.f.red[3];
      float scale = rsqrtf(tot * (1.f / Dz) + 1e-5f);
      if (tid < Dz) {
        float o = val * scale * norm_w[tid];
        sh.f.xs[tid] = o;
        if (br == 0) xn[((size_t)b * Lz + POSz) * Dz + tid] = o;
      }
      __syncthreads();
      const float* ip = br ? ipb : ipf;
      for (int e = tid; e < EDz; e += 256) {
        float acc = 0.f;
        for (int d = 0; d < Dz; ++d) acc += sh.f.xs[d] * ip[d * (2 * EDz) + EDz + e];
        zbuf[((size_t)br * Bz + b) * EDz + e] = acc;
      }
    } else {
      int pt = task - 9;
      int b = pt / Tz, t = pt - b * Tz;
      int l = (t < POSz) ? t : t + 1;
      float* outr = xn + ((size_t)b * Lz + l) * Dz;
      int ntw = n_tweets[b]; if (ntw > Tz) ntw = Tz;
      if (t >= ntw) {
        if (tid < Dz) outr[tid] = 0.f;
      } else {
        int nw = n_words[b * Tz + t]; if (nw > Wz) nw = Wz; if (nw < 1) nw = 1;
        const float* xs = x + ((size_t)(b * Tz + t)) * (Wz * Dz);
        int w = tid >> 3, j = tid & 7;
        float sc = 0.f;
        if (w < nw) {
          for (int d = j * 4; d < Dz; d += 32) {
            float4 xv = *(const float4*)(xs + w * Dz + d);
            float4 wv = *(const float4*)(w_attn + d);
            sc += xv.x * wv.x + xv.y * wv.y + xv.z * wv.z + xv.w * wv.w;
          }
        }
        sc += __shfl_xor(sc, 1); sc += __shfl_xor(sc, 2); sc += __shfl_xor(sc, 4);
        if (j == 0) sh.f.attn[w] = (w < nw) ? (sc + b_attn[0]) : NEG_BIG;
        __syncthreads();
        if (tid < 64) {
          float s = (tid < Wz) ? sh.f.attn[tid] : NEG_BIG;
          float m = s;
#pragma unroll
          for (int o = 32; o; o >>= 1) m = fmaxf(m, __shfl_xor(m, o));
          float e = (s > 0.5f * NEG_BIG) ? __expf(s - m) : 0.f;
          float tot = wave_sum(e);
          if (tid < Wz) sh.f.attn[tid] = e / tot;
        }
        __syncthreads();
        float val = 0.f;
        if (tid < Dz) {
          for (int ww = 0; ww < nw; ++ww) val += sh.f.attn[ww] * xs[ww * Dz + tid];
        }
        float sq = wave_sum(val * val);
        if (lane == 0) sh.f.red[wave] = sq;
        __syncthreads();
        float tot = sh.f.red[0] + sh.f.red[1] + sh.f.red[2] + sh.f.red[3];
        float scale = rsqrtf(tot * (1.f / Dz) + 1e-5f);
        if (tid < Dz) outr[tid] = val * scale * norm_w[tid];
      }
    }
    __syncthreads();
  }
  __threadfence();
  grid.sync();

  // ---------------- Phase 1: in_proj GEMM -> Pbuf ----------------
  for (int task = bid; task < 8 * 56; task += G) {
    int brb = task / 56;
    int rr = task - brb * 56;
    int tt = rr / 7, ee = rr - tt * 7;
    int br = brb >> 2, b = brb & 3;
    int t0 = tt * 64, e0 = ee * 64;
    const float* ip = br ? ipb : ipf;
    int tx = tid & 15, ty = tid >> 4;
    float acc[4][4];
#pragma unroll
    for (int i = 0; i < 4; ++i)
#pragma unroll
      for (int j = 0; j < 4; ++j) acc[i][j] = 0.f;
    int xr = tid >> 2, xc = (tid & 3) * 4;
    int wr = tid >> 4, wc = (tid & 15) * 4;
    int t = t0 + xr;
    bool tok = (t < LPz);
    int l = br ? (Lz - 1 - t) : t;
    const float* xrow = xn + ((size_t)b * Lz + l) * Dz;
    for (int dk = 0; dk < 200; dk += 16) {
      float xv[4], wv[4];
#pragma unroll
      for (int c = 0; c < 4; ++c) {
        int d = dk + xc + c;
        xv[c] = (tok && d < Dz) ? xrow[d] : 0.f;
      }
      int dw = dk + wr;
#pragma unroll
      for (int c = 0; c < 4; ++c) {
        int e = e0 + wc + c;
        wv[c] = (dw < Dz && e < EDz) ? ip[(size_t)dw * (2 * EDz) + e] : 0.f;
      }
      __syncthreads();
#pragma unroll
      for (int c = 0; c < 4; ++c) sh.g.Xs[xc + c][xr] = xv[c];
#pragma unroll
      for (int c = 0; c < 4; ++c) sh.g.Ws[wr][wc + c] = wv[c];
      __syncthreads();
#pragma unroll
      for (int k = 0; k < 16; ++k) {
        float4 a4 = *(const float4*)&sh.g.Xs[k][ty * 4];
        float4 b4 = *(const float4*)&sh.g.Ws[k][tx * 4];
        float av[4] = {a4.x, a4.y, a4.z, a4.w};
        float bv[4] = {b4.x, b4.y, b4.z, b4.w};
#pragma unroll
        for (int i = 0; i < 4; ++i)
#pragma unroll
          for (int j = 0; j < 4; ++j) acc[i][j] += av[i] * bv[j];
      }
    }
#pragma unroll
    for (int j = 0; j < 4; ++j) {
      int e = e0 + tx * 4 + j;
      if (e < EDz) {
        float4 o = make_float4(acc[0][j], acc[1][j], acc[2][j], acc[3][j]);
        *(float4*)&Pbuf[((size_t)brb * EDz + e) * TSTR + t0 + ty * 4] = o;
      }
    }
    __syncthreads();
  }
  __threadfence();
  grid.sync();

  // ---------------- Phase 2: conv+silu -> xp_t ; xproj partials -> dbcp ------
  for (int task = bid; task < 8 * 8 * ESP; task += G) {
    int esp = task % ESP;
    int rem = task / ESP;
    int tc = rem & 7, brb = rem >> 3;
    int br = brb >> 2;
    int t = tc * 64 + lane;
    const float* cw = br ? cwb : cwf;
    const float* cb = br ? cbb : cbf;
    const float* xpj = br ? xpjb : xpjf;
    float accq[45];
#pragma unroll
    for (int q = 0; q < 45; ++q) accq[q] = 0.f;
    const float* Pb = Pbuf + (size_t)brb * EDz * TSTR;
    int e0 = esp * 40 + wave * 10;
#pragma unroll 2
    for (int i = 0; i < 10; ++i) {
      int e = e0 + i;
      const float* pr = Pb + (size_t)e * TSTR;
      float p0 = (t >= 3) ? pr[t - 3] : 0.f;
      float p1 = (t >= 2) ? pr[t - 2] : 0.f;
      float p2 = (t >= 1) ? pr[t - 1] : 0.f;
      float p3 = pr[t];
      float4 c4 = *(const float4*)(cw + e * 4);
      float a = cb[e] + c4.x * p0 + c4.y * p1 + c4.z * p2 + c4.w * p3;
      float sp = a / (1.f + __expf(-a));
      xp_t[((size_t)brb * EDz + e) * TSTR + t] = sp;
      const float* xq = xpj + e * 45;
#pragma unroll
      for (int q = 0; q < 45; ++q) accq[q] += sp * xq[q];
    }
    if (wave == 0) {
#pragma unroll
      for (int q = 0; q < 45; ++q) sh.m.sred[lane][q] = accq[q];
    }
    __syncthreads();
    if (wave == 1) {
#pragma unroll
      for (int q = 0; q < 45; ++q) sh.m.sred[lane][q] += accq[q];
    }
    __syncthreads();
    if (wave == 2) {
#pragma unroll
      for (int q = 0; q < 45; ++q) sh.m.sred[lane][q] += accq[q];
    }
    __syncthreads();
    if (wave == 3) {
#pragma unroll
      for (int q = 0; q < 45; ++q) sh.m.sred[lane][q] += accq[q];
    }
    __syncthreads();
    if (wave == 0) {
      float* dp = dbcp + ((size_t)(esp * 8 + brb) * 45) * TSTR + t;
#pragma unroll
      for (int q = 0; q < 45; ++q) dp[(size_t)q * TSTR] = sh.m.sred[lane][q];
    }
    __syncthreads();
  }
  __threadfence();
  grid.sync();

  // ---------------- Phase 3: sum partials -> dt / Bm / Cend ----------------
  for (int task = bid; task < 8 * 8 * 11; task += G) {
    int egrp = task % 11;
    int rem = task / 11;
    int tc = rem & 7, brb = rem >> 3;
    int br = brb >> 2;
    int t = tc * 64 + lane;
    const size_t espstr = (size_t)8 * 45 * TSTR;
    if (egrp == 10) {
      for (int idx = tid; idx < 16 * 64; idx += 256) {
        int n = idx >> 6, tl = idx & 63;
        size_t base = ((size_t)brb * 45 + 13 + n) * TSTR + tc * 64 + tl;
        float s = 0.f;
#pragma unroll
        for (int esp = 0; esp < ESP; ++esp) s += dbcp[base + esp * espstr];
        Bm_t[((size_t)brb * Nz + n) * TSTR + tc * 64 + tl] = s;
      }
      if (tc == 7 && tid < Nz) {
        size_t base = ((size_t)brb * 45 + 29 + tid) * TSTR + POSz;
        float s = 0.f;
#pragma unroll
        for (int esp = 0; esp < ESP; ++esp) s += dbcp[base + esp * espstr];
        Cend[brb * Nz + tid] = s;
      }
    } else {
      for (int idx = tid; idx < DTRz * 64; idx += 256) {
        int q = idx >> 6, tl = idx & 63;
        size_t base = ((size_t)brb * 45 + q) * TSTR + tc * 64 + tl;
        float s = 0.f;
#pragma unroll
        for (int esp = 0; esp < ESP; ++esp) s += dbcp[base + esp * espstr];
        sh.d.dfin[q][tl] = s;
      }
      __syncthreads();
      const float* dtw = br ? dtwb : dtwf;
      const float* dtb = br ? dtbb : dtbf;
      float dq[DTRz];
#pragma unroll
      for (int q = 0; q < DTRz; ++q) dq[q] = sh.d.dfin[q][lane];
      int e0 = egrp * 40 + wave * 10;
#pragma unroll 2
      for (int i = 0; i < 10; ++i) {
        int e = e0 + i;
        float s = dtb[e];
#pragma unroll
        for (int q = 0; q < DTRz; ++q) s += dq[q] * dtw[q * EDz + e];
        float dtv = (s > 20.f) ? s : log1pf(__expf(s));
        dt_t[((size_t)brb * EDz + e) * TSTR + t] = dtv;
      }
    }
    __syncthreads();
  }
  __threadfence();
  grid.sync();

  // ---------------- Phase 4: scan (one wave per (br,b,e)) ----------------
  for (int task = bid * 4 + wave; task < 2 * Bz * EDz; task += G * 4) {
    int br = task / (Bz * EDz);
    int rem = task - br * (Bz * EDz);
    int b = rem / EDz, e = rem - b * EDz;
    const float* A_log = br ? Alogb : Alogf;
    const float* Dp = br ? Dpb : Dpf;
    float A[Nz];
    {
      const float4* ap = (const float4*)(A_log + e * Nz);
#pragma unroll
      for (int q = 0; q < 4; ++q) {
        float4 a4 = ap[q];
        A[q * 4 + 0] = -__expf(a4.x); A[q * 4 + 1] = -__expf(a4.y);
        A[q * 4 + 2] = -__expf(a4.z); A[q * 4 + 3] = -__expf(a4.w);
      }
    }
    size_t base = ((size_t)(br * Bz + b) * EDz + e) * TSTR;
    const float* dtp = dt_t + base;
    const float* xpp = xp_t + base;
    const float* bmp = Bm_t + (size_t)(br * Bz + b) * Nz * TSTR;
    float loc = 0.f;
#pragma unroll
    for (int c = 0; c < 8; ++c) {
      int t = c * 64 + lane;
      if (t < LPz) loc += dtp[t];
    }
    float Stot = wave_sum(loc);
    float acc[Nz];
#pragma unroll
    for (int n = 0; n < Nz; ++n) acc[n] = 0.f;
    float carry = 0.f;
    for (int c = 0; c < 8; ++c) {
      int t = c * 64 + lane;
      bool act = t < LPz;
      float dtt = 0.f, xv = 0.f;
      if (act) { dtt = dtp[t]; xv = xpp[t]; }
      float s = dtt;
#pragma unroll
      for (int o = 1; o < 64; o <<= 1) {
        float u = __shfl_up(s, o);
        s += (lane >= o) ? u : 0.f;
      }
      float S = carry + s;
      carry += __shfl(s, 63);
      float wt = dtt * xv;
      float decay = Stot - S;
#pragma unroll
      for (int n = 0; n < Nz; ++n) {
        float bv = 0.f;
        if (act) bv = bmp[n * TSTR + t];
        acc[n] += __expf(A[n] * decay) * wt * bv;
      }
    }
#pragma unroll
    for (int o = 32; o; o >>= 1) {
#pragma unroll
      for (int n = 0; n < Nz; ++n) acc[n] += __shfl_xor(acc[n], o);
    }
    if (lane == 0) {
      float y = Dp[e] * xpp[LPz - 1];
#pragma unroll
      for (int n = 0; n < Nz; ++n) y += Cend[(br * Bz + b) * Nz + n] * acc[n];
      float zz = zbuf[((size_t)br * Bz + b) * EDz + e];
      float sz = zz / (1.f + __expf(-zz));
      ybuf[((size_t)br * Bz + b) * EDz + e] = y * sz * vbuf[e];
    }
  }
  __threadfence();
  grid.sync();

  // ---------------- Phase 5: final ----------------
  if (bid == 0) {
    int b = tid >> 6;
    float acc = 0.f;
    for (int e = lane; e < EDz; e += 64)
      acc += ybuf[(size_t)b * EDz + e] + ybuf[(size_t)(Bz + b) * EDz + e];
    for (int d = lane; d < Dz; d += 64) acc += cls[d] * head_w[d];
    acc = wave_sum(acc);
    if (lane == 0) outp[b] = 1.f / (1.f + __expf(-(acc + head_b[0])));
  }
}

extern "C" void kernel_launch(void* const* d_in, const int* in_sizes, int n_in,
                              void* d_out, int out_size, void* d_ws, size_t ws_size,
                              hipStream_t stream) {
  const float* x_ = (const float*)d_in[0];
  const int* ntw_ = (const int*)d_in[1];
  const int* nwd_ = (const int*)d_in[2];
  const float* cls_ = (const float*)d_in[3];
  const float* wat_ = (const float*)d_in[4];
  const float* bat_ = (const float*)d_in[5];
  const float* nw_ = (const float*)d_in[6];
  const float* ipf_ = (const float*)d_in[7];
  const float* cwf_ = (const float*)d_in[8];
  const float* cbf_ = (const float*)d_in[9];
  const float* xpjf_ = (const float*)d_in[10];
  const float* dtwf_ = (const float*)d_in[11];
  const float* dtbf_ = (const float*)d_in[12];
  const float* Alf_ = (const float*)d_in[13];
  const float* Dpf_ = (const float*)d_in[14];
  const float* ipb_ = (const float*)d_in[15];
  const float* cwb_ = (const float*)d_in[16];
  const float* cbb_ = (const float*)d_in[17];
  const float* xpjb_ = (const float*)d_in[18];
  const float* dtwb_ = (const float*)d_in[19];
  const float* dtbb_ = (const float*)d_in[20];
  const float* Alb_ = (const float*)d_in[21];
  const float* Dpb_ = (const float*)d_in[22];
  const float* opj_ = (const float*)d_in[23];
  const float* hw_ = (const float*)d_in[24];
  const float* hb_ = (const float*)d_in[25];
  float* out_ = (float*)d_out;

  float* ws = (float*)d_ws;
  float* xn_ = ws;                           // 800800
  float* Pbuf_ = xn_ + 800800;               // 1638400
  float* xpt_ = Pbuf_ + 1638400;             // 1638400
  float* dtt_ = xpt_ + 1638400;              // 1638400
  float* Bmt_ = dtt_ + 1638400;              // 65536
  float* dbcp_ = Bmt_ + 65536;               // 1843200
  float* Cend_ = dbcp_ + 1843200;            // 128
  float* zbuf_ = Cend_ + 128;                // 3200
  float* vbuf_ = zbuf_ + 3200;               // 400
  float* ybuf_ = vbuf_ + 400;                // 3200

  int occ = 0;
  hipOccupancyMaxActiveBlocksPerMultiprocessor(&occ, k_all, 256, 0);
  if (occ < 1) occ = 1;
  int G = occ * 256;
  if (G > 1024) G = 1024;

  void* args[] = {
    (void*)&x_, (void*)&ntw_, (void*)&nwd_, (void*)&wat_, (void*)&bat_,
    (void*)&nw_, (void*)&cls_, (void*)&opj_, (void*)&hw_, (void*)&hb_,
    (void*)&ipf_, (void*)&ipb_, (void*)&cwf_, (void*)&cwb_, (void*)&cbf_,
    (void*)&cbb_, (void*)&xpjf_, (void*)&xpjb_, (void*)&dtwf_, (void*)&dtwb_,
    (void*)&dtbf_, (void*)&dtbb_, (void*)&Alf_, (void*)&Alb_, (void*)&Dpf_,
    (void*)&Dpb_, (void*)&xn_, (void*)&Pbuf_, (void*)&xpt_, (void*)&dtt_,
    (void*)&Bmt_, (void*)&dbcp_, (void*)&Cend_, (void*)&zbuf_, (void*)&vbuf_,
    (void*)&ybuf_, (void*)&out_
  };
  hipLaunchCooperativeKernel(k_all, dim3(G), dim3(256), args, 0, stream);
}

// Round 8
// 107.412 us; speedup vs baseline: 3.8851x; 3.8851x over previous
//
#include <hip/hip_runtime.h>
#include <cmath>

#define Bz 4
#define Tz 1000
#define Wz 32
#define Dz 200
#define EDz 400
#define Nz 16
#define DTRz 13
#define Lz 1001
#define POSz 500
#define LPz 501
#define TSTR 512
#define ESP 10      // e-splits in k_mid (40 e each)
#define NEG_BIG -1e30f

__device__ __forceinline__ float wave_sum(float v) {
#pragma unroll
  for (int o = 32; o; o >>= 1) v += __shfl_xor(v, o);
  return v;
}

// grid = 9 + 1000 blocks.
// blocks 0..8: setup (v[e], CLS row -> xn[POS], z).
// blocks 9..1008: word-pool, ONE WAVE PER TWEET (4 tweets/block), no LDS/syncs.
__global__ __launch_bounds__(256) void k_front(
    const float* __restrict__ x, const int* __restrict__ n_tweets,
    const int* __restrict__ n_words, const float* __restrict__ w_attn,
    const float* __restrict__ b_attn, const float* __restrict__ norm_w,
    const float* __restrict__ cls, const float* __restrict__ out_proj,
    const float* __restrict__ head_w, const float* __restrict__ ipf,
    const float* __restrict__ ipb, float* __restrict__ xn,
    float* __restrict__ zbuf, float* __restrict__ vbuf) {
  int bid = blockIdx.x;
  int tid = threadIdx.x;
  int wave = tid >> 6, lane = tid & 63;
  if (bid < 9) {
    if (bid == 0) {
      __shared__ float hw[Dz];
      if (tid < Dz) hw[tid] = head_w[tid];
      __syncthreads();
      for (int e = tid; e < EDz; e += 256) {
        float acc = 0.f;
        for (int d = 0; d < Dz; d += 4) {
          float4 ov = *(const float4*)(out_proj + e * Dz + d);
          acc += ov.x * hw[d] + ov.y * hw[d + 1] + ov.z * hw[d + 2] + ov.w * hw[d + 3];
        }
        vbuf[e] = acc;
      }
      return;
    }
    int id = bid - 1;
    int br = id >> 2, b = id & 3;
    __shared__ float xs[Dz];
    __shared__ float s_red[4];
    float val = (tid < Dz) ? cls[tid] : 0.f;
    float sq = wave_sum(val * val);
    if ((tid & 63) == 0) s_red[tid >> 6] = sq;
    __syncthreads();
    float tot = s_red[0] + s_red[1] + s_red[2] + s_red[3];
    float scale = rsqrtf(tot * (1.f / Dz) + 1e-5f);
    if (tid < Dz) {
      float o = val * scale * norm_w[tid];
      xs[tid] = o;
      if (br == 0) xn[((size_t)b * Lz + POSz) * Dz + tid] = o;
    }
    __syncthreads();
    const float* ip = br ? ipb : ipf;
    for (int e = tid; e < EDz; e += 256) {
      float acc = 0.f;
      for (int d = 0; d < Dz; ++d) acc += xs[d] * ip[d * (2 * EDz) + EDz + e];
      zbuf[((size_t)br * Bz + b) * EDz + e] = acc;
    }
    return;
  }
  // ---- pool: one wave per (b,t) ----
  int bt = (bid - 9) * 4 + wave;          // 0..3999
  int b = bt / Tz, t = bt - b * Tz;
  int l = (t < POSz) ? t : t + 1;
  float* outr = xn + ((size_t)b * Lz + l) * Dz;
  int ntw = n_tweets[b]; if (ntw > Tz) ntw = Tz;
  if (t >= ntw) {
    if (lane < 50) *(float4*)(outr + lane * 4) = make_float4(0.f, 0.f, 0.f, 0.f);
    return;
  }
  int nw = n_words[b * Tz + t]; if (nw > Wz) nw = Wz; if (nw < 1) nw = 1;
  const float* xs = x + ((size_t)(b * Tz + t)) * (Wz * Dz);
  int h = lane & 1, w = lane >> 1;
  // phase A: scores, 2 lanes per word, each lane 100 contiguous d's
  float sc = 0.f;
  if (w < nw) {
    const float* xr = xs + w * Dz + h * 100;
    const float* wr = w_attn + h * 100;
#pragma unroll
    for (int i = 0; i < 25; ++i) {
      float4 xv = *(const float4*)(xr + i * 4);
      float4 wv = *(const float4*)(wr + i * 4);
      sc += xv.x * wv.x + xv.y * wv.y + xv.z * wv.z + xv.w * wv.w;
    }
  }
  sc += __shfl_xor(sc, 1);
  float scv = (w < nw) ? (sc + b_attn[0]) : NEG_BIG;
  // softmax across the wave (words duplicated on lane pairs)
  float m = scv;
#pragma unroll
  for (int o = 32; o; o >>= 1) m = fmaxf(m, __shfl_xor(m, o));
  float en = __expf(scv - m);             // 0 for invalid words
  float es = (h == 0) ? en : 0.f;
  float tot = wave_sum(es);
  en /= tot;
  // phase C: weighted sum, lane = d-chunk (50 float4 chunks)
  float4 val = make_float4(0.f, 0.f, 0.f, 0.f);
  const float* xc = xs + lane * 4;
  for (int ww = 0; ww < nw; ++ww) {
    float aw = __shfl(en, 2 * ww);
    if (lane < 50) {
      float4 xv = *(const float4*)(xc + ww * Dz);
      val.x += aw * xv.x; val.y += aw * xv.y;
      val.z += aw * xv.z; val.w += aw * xv.w;
    }
  }
  float sq = (lane < 50) ? (val.x * val.x + val.y * val.y + val.z * val.z + val.w * val.w) : 0.f;
  sq = wave_sum(sq);
  float scale = rsqrtf(sq * (1.f / Dz) + 1e-5f);
  if (lane < 50) {
    float4 nw4 = *(const float4*)(norm_w + lane * 4);
    float4 o = make_float4(val.x * scale * nw4.x, val.y * scale * nw4.y,
                           val.z * scale * nw4.z, val.w * scale * nw4.w);
    *(float4*)(outr + lane * 4) = o;
  }
}

// Register-tiled GEMM: P^T[brb][e][t] = sum_d W[d][e] * X[t][d].
// 64t x 64e tile per block, 256 threads, 4x4 micro-tile, K-step 16 in LDS.
__global__ __launch_bounds__(256) void k_gemm(
    const float* __restrict__ xn, const float* __restrict__ ipf,
    const float* __restrict__ ipb, float* __restrict__ P) {
  int bid = blockIdx.x;
  int brb = bid / 56;
  int rr = bid - brb * 56;
  int tt = rr / 7, ee = rr - tt * 7;
  int br = brb >> 2, b = brb & 3;
  int t0 = tt * 64, e0 = ee * 64;
  const float* ip = br ? ipb : ipf;
  int tid = threadIdx.x;
  int tx = tid & 15, ty = tid >> 4;

  __shared__ float Xs[16][64 + 4];
  __shared__ float Ws[16][64 + 4];

  float acc[4][4];
#pragma unroll
  for (int i = 0; i < 4; ++i)
#pragma unroll
    for (int j = 0; j < 4; ++j) acc[i][j] = 0.f;

  int xr = tid >> 2, xc = (tid & 3) * 4;
  int wr = tid >> 4, wc = (tid & 15) * 4;
  int t = t0 + xr;
  bool tok = (t < LPz);
  int l = br ? (Lz - 1 - t) : t;
  const float* xrow = xn + ((size_t)b * Lz + l) * Dz;

  for (int dk = 0; dk < 200; dk += 16) {
    float xv[4], wv[4];
#pragma unroll
    for (int c = 0; c < 4; ++c) {
      int d = dk + xc + c;
      xv[c] = (tok && d < Dz) ? xrow[d] : 0.f;
    }
    int dw = dk + wr;
#pragma unroll
    for (int c = 0; c < 4; ++c) {
      int e = e0 + wc + c;
      wv[c] = (dw < Dz && e < EDz) ? ip[(size_t)dw * (2 * EDz) + e] : 0.f;
    }
    __syncthreads();
#pragma unroll
    for (int c = 0; c < 4; ++c) Xs[xc + c][xr] = xv[c];
#pragma unroll
    for (int c = 0; c < 4; ++c) Ws[wr][wc + c] = wv[c];
    __syncthreads();
#pragma unroll
    for (int k = 0; k < 16; ++k) {
      float4 a4 = *(const float4*)&Xs[k][ty * 4];
      float4 b4 = *(const float4*)&Ws[k][tx * 4];
      float av[4] = {a4.x, a4.y, a4.z, a4.w};
      float bv[4] = {b4.x, b4.y, b4.z, b4.w};
#pragma unroll
      for (int i = 0; i < 4; ++i)
#pragma unroll
        for (int j = 0; j < 4; ++j) acc[i][j] += av[i] * bv[j];
    }
  }
#pragma unroll
  for (int j = 0; j < 4; ++j) {
    int e = e0 + tx * 4 + j;
    if (e < EDz) {
      float4 o = make_float4(acc[0][j], acc[1][j], acc[2][j], acc[3][j]);
      *(float4*)&P[((size_t)brb * EDz + e) * TSTR + t0 + ty * 4] = o;
    }
  }
}

// conv+silu -> xp_t ; xproj partial over 40 e's -> dbcpart[esp][brb][45][t].
// grid = brb(8) x tchunk(8) x esp(10) = 640 blocks, 256 threads (4 waves).
__global__ __launch_bounds__(256) void k_mid(
    const float* __restrict__ P,
    const float* __restrict__ cwf, const float* __restrict__ cwb,
    const float* __restrict__ cbf, const float* __restrict__ cbb,
    const float* __restrict__ xpjf, const float* __restrict__ xpjb,
    float* __restrict__ xp_t, float* __restrict__ dbcp) {
  int bid = blockIdx.x;
  int esp = bid % ESP;
  int rem = bid / ESP;
  int tc = rem & 7, brb = rem >> 3;
  int br = brb >> 2;
  int tid = threadIdx.x;
  int wave = tid >> 6, lane = tid & 63;
  int t = tc * 64 + lane;
  const float* cw = br ? cwb : cwf;
  const float* cb = br ? cbb : cbf;
  const float* xpj = br ? xpjb : xpjf;

  __shared__ float sred[4][64][45];

  float accq[45];
#pragma unroll
  for (int q = 0; q < 45; ++q) accq[q] = 0.f;

  const float* Pb = P + (size_t)brb * EDz * TSTR;
  int e0 = esp * 40 + wave * 10;
#pragma unroll 2
  for (int i = 0; i < 10; ++i) {
    int e = e0 + i;
    const float* pr = Pb + (size_t)e * TSTR;
    float p0 = (t >= 3) ? pr[t - 3] : 0.f;
    float p1 = (t >= 2) ? pr[t - 2] : 0.f;
    float p2 = (t >= 1) ? pr[t - 1] : 0.f;
    float p3 = pr[t];
    float4 c4 = *(const float4*)(cw + e * 4);
    float a = cb[e] + c4.x * p0 + c4.y * p1 + c4.z * p2 + c4.w * p3;
    float sp = a / (1.f + __expf(-a));
    xp_t[((size_t)brb * EDz + e) * TSTR + t] = sp;
    const float* xq = xpj + e * 45;
#pragma unroll
    for (int q = 0; q < 45; ++q) accq[q] += sp * xq[q];
  }
#pragma unroll
  for (int q = 0; q < 45; ++q) sred[wave][lane][q] = accq[q];
  __syncthreads();
  if (wave < 2) {
#pragma unroll
    for (int q = 0; q < 45; ++q)
      sred[wave][lane][q] += sred[wave + 2][lane][q];
  }
  __syncthreads();
  if (wave == 0) {
    float* dp = dbcp + ((size_t)(esp * 8 + brb) * 45) * TSTR + t;
#pragma unroll
    for (int q = 0; q < 45; ++q)
      dp[(size_t)q * TSTR] = sred[0][lane][q] + sred[1][lane][q];
  }
}

// Sum ESP partials and finish dt / Bm / Cend with high TLP.
// grid = brb(8) x tc(8) x egrp(11) = 704 blocks, 256 threads.
// egrp 0..9: dt for 40 e's each. egrp 10: Bm_t (+Cend when tc==7).
__global__ __launch_bounds__(256) void k_dt2(
    const float* __restrict__ dbcp,
    const float* __restrict__ dtwf, const float* __restrict__ dtwb,
    const float* __restrict__ dtbf, const float* __restrict__ dtbb,
    float* __restrict__ dt_t, float* __restrict__ Bm_t,
    float* __restrict__ Cend) {
  int bid = blockIdx.x;
  int egrp = bid % 11;
  int rem = bid / 11;
  int tc = rem & 7, brb = rem >> 3;
  int br = brb >> 2;
  int tid = threadIdx.x;
  int wave = tid >> 6, lane = tid & 63;
  int t = tc * 64 + lane;
  const size_t espstr = (size_t)8 * 45 * TSTR;

  if (egrp == 10) {
    for (int idx = tid; idx < 16 * 64; idx += 256) {
      int n = idx >> 6, tl = idx & 63;
      size_t base = ((size_t)brb * 45 + 13 + n) * TSTR + tc * 64 + tl;
      float s = 0.f;
#pragma unroll
      for (int esp = 0; esp < ESP; ++esp) s += dbcp[base + esp * espstr];
      Bm_t[((size_t)brb * Nz + n) * TSTR + tc * 64 + tl] = s;
    }
    if (tc == 7 && tid < Nz) {
      size_t base = ((size_t)brb * 45 + 29 + tid) * TSTR + POSz;
      float s = 0.f;
#pragma unroll
      for (int esp = 0; esp < ESP; ++esp) s += dbcp[base + esp * espstr];
      Cend[brb * Nz + tid] = s;
    }
    return;
  }

  __shared__ float dfin[DTRz][64];
  for (int idx = tid; idx < DTRz * 64; idx += 256) {
    int q = idx >> 6, tl = idx & 63;
    size_t base = ((size_t)brb * 45 + q) * TSTR + tc * 64 + tl;
    float s = 0.f;
#pragma unroll
    for (int esp = 0; esp < ESP; ++esp) s += dbcp[base + esp * espstr];
    dfin[q][tl] = s;
  }
  __syncthreads();
  const float* dtw = br ? dtwb : dtwf;
  const float* dtb = br ? dtbb : dtbf;
  float dq[DTRz];
#pragma unroll
  for (int q = 0; q < DTRz; ++q) dq[q] = dfin[q][lane];
  int e0 = egrp * 40 + wave * 10;
#pragma unroll 2
  for (int i = 0; i < 10; ++i) {
    int e = e0 + i;
    float s = dtb[e];
#pragma unroll
    for (int q = 0; q < DTRz; ++q) s += dq[q] * dtw[q * EDz + e];
    float dtv = (s > 20.f) ? s : log1pf(__expf(s));
    dt_t[((size_t)brb * EDz + e) * TSTR + t] = dtv;
  }
}

// h[end,e,n] = sum_t exp(A_n*(Stot-S_t))*dt_t*Bm[t,n]*xp_t, lane-contiguous.
__global__ __launch_bounds__(64) void k_scan(
    const float* __restrict__ xp_t, const float* __restrict__ dt_t,
    const float* __restrict__ Bm_t, const float* __restrict__ Cend,
    const float* __restrict__ Alogf, const float* __restrict__ Alogb,
    const float* __restrict__ Dpf, const float* __restrict__ Dpb,
    const float* __restrict__ zbuf, const float* __restrict__ vbuf,
    float* __restrict__ ybuf) {
  int blk = blockIdx.x;
  int br = blk / (Bz * EDz);
  int rem = blk - br * (Bz * EDz);
  int b = rem / EDz, e = rem - b * EDz;
  int lane = threadIdx.x;
  const float* A_log = br ? Alogb : Alogf;
  const float* Dp = br ? Dpb : Dpf;
  float A[Nz];
  {
    const float4* ap = (const float4*)(A_log + e * Nz);
#pragma unroll
    for (int q = 0; q < 4; ++q) {
      float4 a4 = ap[q];
      A[q * 4 + 0] = -__expf(a4.x); A[q * 4 + 1] = -__expf(a4.y);
      A[q * 4 + 2] = -__expf(a4.z); A[q * 4 + 3] = -__expf(a4.w);
    }
  }
  size_t base = ((size_t)(br * Bz + b) * EDz + e) * TSTR;
  const float* dtp = dt_t + base;
  const float* xpp = xp_t + base;
  const float* bmp = Bm_t + (size_t)(br * Bz + b) * Nz * TSTR;
  float loc = 0.f;
#pragma unroll
  for (int c = 0; c < 8; ++c) {
    int t = c * 64 + lane;
    if (t < LPz) loc += dtp[t];
  }
  float Stot = wave_sum(loc);
  float acc[Nz];
#pragma unroll
  for (int n = 0; n < Nz; ++n) acc[n] = 0.f;
  float carry = 0.f;
  for (int c = 0; c < 8; ++c) {
    int t = c * 64 + lane;
    bool act = t < LPz;
    float dtt = 0.f, xv = 0.f;
    if (act) { dtt = dtp[t]; xv = xpp[t]; }
    float s = dtt;
#pragma unroll
    for (int o = 1; o < 64; o <<= 1) {
      float u = __shfl_up(s, o);
      s += (lane >= o) ? u : 0.f;
    }
    float S = carry + s;
    carry += __shfl(s, 63);
    float wt = dtt * xv;
    float decay = Stot - S;  // >= 0, A<0 => exp<=1
#pragma unroll
    for (int n = 0; n < Nz; ++n) {
      float bv = 0.f;
      if (act) bv = bmp[n * TSTR + t];
      acc[n] += __expf(A[n] * decay) * wt * bv;
    }
  }
#pragma unroll
  for (int o = 32; o; o >>= 1) {
#pragma unroll
    for (int n = 0; n < Nz; ++n) acc[n] += __shfl_xor(acc[n], o);
  }
  if (lane == 0) {
    float y = Dp[e] * xpp[LPz - 1];
#pragma unroll
    for (int n = 0; n < Nz; ++n) y += Cend[(br * Bz + b) * Nz + n] * acc[n];
    float zz = zbuf[((size_t)br * Bz + b) * EDz + e];
    float sz = zz / (1.f + __expf(-zz));
    ybuf[((size_t)br * Bz + b) * EDz + e] = y * sz * vbuf[e];
  }
}

__global__ __launch_bounds__(256) void k_final(
    const float* __restrict__ cls, const float* __restrict__ head_w,
    const float* __restrict__ head_b, const float* __restrict__ ybuf,
    float* __restrict__ out) {
  int tid = threadIdx.x;
  int b = tid >> 6, lane = tid & 63;
  float acc = 0.f;
  for (int e = lane; e < EDz; e += 64)
    acc += ybuf[(size_t)b * EDz + e] + ybuf[(size_t)(Bz + b) * EDz + e];
  for (int d = lane; d < Dz; d += 64) acc += cls[d] * head_w[d];
  acc = wave_sum(acc);
  if (lane == 0) out[b] = 1.f / (1.f + __expf(-(acc + head_b[0])));
}

extern "C" void kernel_launch(void* const* d_in, const int* in_sizes, int n_in,
                              void* d_out, int out_size, void* d_ws, size_t ws_size,
                              hipStream_t stream) {
  const float* input_ids = (const float*)d_in[0];
  const int* n_tweets = (const int*)d_in[1];
  const int* n_words = (const int*)d_in[2];
  const float* cls = (const float*)d_in[3];
  const float* w_attn = (const float*)d_in[4];
  const float* b_attn = (const float*)d_in[5];
  const float* norm_w = (const float*)d_in[6];
  const float* ip[2] = {(const float*)d_in[7], (const float*)d_in[15]};
  const float* cw[2] = {(const float*)d_in[8], (const float*)d_in[16]};
  const float* cb[2] = {(const float*)d_in[9], (const float*)d_in[17]};
  const float* xpj[2] = {(const float*)d_in[10], (const float*)d_in[18]};
  const float* dtw[2] = {(const float*)d_in[11], (const float*)d_in[19]};
  const float* dtbp[2] = {(const float*)d_in[12], (const float*)d_in[20]};
  const float* Alog[2] = {(const float*)d_in[13], (const float*)d_in[21]};
  const float* Dpp[2] = {(const float*)d_in[14], (const float*)d_in[22]};
  const float* out_proj = (const float*)d_in[23];
  const float* head_w = (const float*)d_in[24];
  const float* head_b = (const float*)d_in[25];
  float* out = (float*)d_out;

  float* ws = (float*)d_ws;
  float* xn = ws;                           // 800800
  float* Pbuf = xn + 800800;                // 1638400
  float* xp_t = Pbuf + 1638400;             // 1638400
  float* dt_t = xp_t + 1638400;             // 1638400
  float* Bm_t = dt_t + 1638400;             // 65536
  float* dbcp = Bm_t + 65536;               // 1843200
  float* Cend = dbcp + 1843200;             // 128
  float* zbuf = Cend + 128;                 // 3200
  float* vbuf = zbuf + 3200;                // 400
  float* ybuf = vbuf + 400;                 // 3200

  hipLaunchKernelGGL(k_front, dim3(9 + Bz * Tz / 4), dim3(256), 0, stream,
                     input_ids, n_tweets, n_words, w_attn, b_attn, norm_w,
                     cls, out_proj, head_w, ip[0], ip[1], xn, zbuf, vbuf);
  hipLaunchKernelGGL(k_gemm, dim3(2 * Bz * 8 * 7), dim3(256), 0, stream,
                     xn, ip[0], ip[1], Pbuf);
  hipLaunchKernelGGL(k_mid, dim3(2 * Bz * 8 * ESP), dim3(256), 0, stream,
                     Pbuf, cw[0], cw[1], cb[0], cb[1], xpj[0], xpj[1],
                     xp_t, dbcp);
  hipLaunchKernelGGL(k_dt2, dim3(2 * Bz * 8 * 11), dim3(256), 0, stream,
                     dbcp, dtw[0], dtw[1], dtbp[0], dtbp[1],
                     dt_t, Bm_t, Cend);
  hipLaunchKernelGGL(k_scan, dim3(2 * Bz * EDz), dim3(64), 0, stream,
                     xp_t, dt_t, Bm_t, Cend, Alog[0], Alog[1], Dpp[0], Dpp[1],
                     zbuf, vbuf, ybuf);
  hipLaunchKernelGGL(k_final, dim3(1), dim3(256), 0, stream,
                     cls, head_w, head_b, ybuf, out);
}